// Round 1
// baseline (4581.434 us; speedup 1.0000x reference)
//
#include <hip/hip_runtime.h>
#include <hip/hip_bf16.h>
#include <math.h>

// Problem constants
#define NLAYERS 6
#define DMODEL  1024
#define NHEADS  16
#define DHEAD   64
#define DMLP    4096
#define PSZ     16
#define HWN     14
#define LTOK    196
#define NKEEP   98
#define NIMG    32
#define SEQ     99              // 1 cls + 98 kept
#define NS      (NIMG * SEQ)    // 3168
#define NP      (NIMG * LTOK)   // 6272
#define PDIM    768             // 16*16*3

typedef __attribute__((ext_vector_type(8))) short short8;
typedef __attribute__((ext_vector_type(4))) float f32x4;

// ---------------------------------------------------------------------------
// Weight convert + transpose: W (K x N) fp32 -> Wt (N x K) bf16, batched on z
// ---------------------------------------------------------------------------
__global__ __launch_bounds__(256) void conv_transpose(
    const float* __restrict__ W, __hip_bfloat16* __restrict__ Wt, int K, int N)
{
    __shared__ float tile[32][33];
    size_t moff = (size_t)blockIdx.z * K * N;
    W += moff; Wt += moff;
    int n0 = blockIdx.x * 32, k0 = blockIdx.y * 32;
    int tx = threadIdx.x & 31, ty = threadIdx.x >> 5;  // 32 x 8
#pragma unroll
    for (int i = 0; i < 4; ++i)
        tile[ty + i * 8][tx] = W[(size_t)(k0 + ty + i * 8) * N + n0 + tx];
    __syncthreads();
#pragma unroll
    for (int i = 0; i < 4; ++i)
        Wt[(size_t)(n0 + ty + i * 8) * K + k0 + tx] = __float2bfloat16(tile[tx][ty + i * 8]);
}

// ---------------------------------------------------------------------------
// argsort(noise) per image via rank counting; mask written straight to d_out
// ---------------------------------------------------------------------------
__global__ __launch_bounds__(256) void sort_kernel(
    const float* __restrict__ noise, int* __restrict__ ids_keep, float* __restrict__ mask)
{
    int n = blockIdx.x, tid = threadIdx.x;
    __shared__ float nz[LTOK];
    if (tid < LTOK) nz[tid] = noise[n * LTOK + tid];
    __syncthreads();
    if (tid < LTOK) {
        float val = nz[tid];
        int rank = 0;
        for (int j = 0; j < LTOK; ++j) {
            float vj = nz[j];
            rank += (vj < val) || (vj == val && j < tid);
        }
        // mask_out[n][l] = mask_in[rank(l)]; mask_in[i] = (i < KEEP) ? 0 : 1
        mask[n * LTOK + tid] = (rank < NKEEP) ? 0.0f : 1.0f;
        if (rank < NKEEP) ids_keep[n * NKEEP + rank] = tid;  // ids_shuffle[rank] = l
    }
}

// ---------------------------------------------------------------------------
// Patchify: imgs (N,224,224,3) -> Apatch (N*196, 768) bf16
// token l = hy*14+hx ; feature = (py*16+px)*3+c
// ---------------------------------------------------------------------------
__global__ __launch_bounds__(256) void patchify(
    const float* __restrict__ imgs, __hip_bfloat16* __restrict__ Ap)
{
    int row = blockIdx.x, tid = threadIdx.x;       // 256 threads = 16x16 pixels
    int n = row / LTOK, l = row % LTOK;
    int hy = l / HWN, hx = l % HWN;
    int py = tid >> 4, px = tid & 15;
    const float* src = imgs + (((size_t)(n * 224 + hy * 16 + py)) * 224 + hx * 16 + px) * 3;
    __hip_bfloat16* dst = Ap + (size_t)row * PDIM + tid * 3;
    dst[0] = __float2bfloat16(src[0]);
    dst[1] = __float2bfloat16(src[1]);
    dst[2] = __float2bfloat16(src[2]);
}

// ---------------------------------------------------------------------------
// Gather kept tokens + prepend cls: x (NS, D) fp32
// ---------------------------------------------------------------------------
__global__ __launch_bounds__(256) void gather_cls(
    const float* __restrict__ x0, const float* __restrict__ cls,
    const int* __restrict__ ids_keep, float* __restrict__ x)
{
    int row = blockIdx.x, tid = threadIdx.x;
    int n = row / SEQ, s = row % SEQ;
    const float* src = (s == 0) ? cls
        : x0 + ((size_t)n * LTOK + ids_keep[n * NKEEP + (s - 1)]) * DMODEL;
    reinterpret_cast<float4*>(x + (size_t)row * DMODEL)[tid] =
        reinterpret_cast<const float4*>(src)[tid];
}

// ---------------------------------------------------------------------------
// LayerNorm: one block per row (D=1024, 256 thr x 4). OUTMODE 0: fp32, 1: bf16
// ---------------------------------------------------------------------------
template <int OUTMODE>
__global__ __launch_bounds__(256) void ln_kernel(
    const float* __restrict__ x, const float* __restrict__ s, const float* __restrict__ b,
    float* __restrict__ of, __hip_bfloat16* __restrict__ ob)
{
    int row = blockIdx.x, tid = threadIdx.x;
    int lane = tid & 63, wid = tid >> 6;
    float4 t = reinterpret_cast<const float4*>(x + (size_t)row * DMODEL)[tid];
    float sum = t.x + t.y + t.z + t.w;
    float sq  = t.x * t.x + t.y * t.y + t.z * t.z + t.w * t.w;
#pragma unroll
    for (int m = 1; m < 64; m <<= 1) { sum += __shfl_xor(sum, m); sq += __shfl_xor(sq, m); }
    __shared__ float sm[8];
    if (lane == 0) { sm[wid] = sum; sm[4 + wid] = sq; }
    __syncthreads();
    sum = sm[0] + sm[1] + sm[2] + sm[3];
    sq  = sm[4] + sm[5] + sm[6] + sm[7];
    float mean = sum * (1.0f / DMODEL);
    float var  = sq * (1.0f / DMODEL) - mean * mean;
    float rstd = rsqrtf(var + 1e-6f);
    float4 sv = reinterpret_cast<const float4*>(s)[tid];
    float4 bv = reinterpret_cast<const float4*>(b)[tid];
    float o0 = (t.x - mean) * rstd * sv.x + bv.x;
    float o1 = (t.y - mean) * rstd * sv.y + bv.y;
    float o2 = (t.z - mean) * rstd * sv.z + bv.z;
    float o3 = (t.w - mean) * rstd * sv.w + bv.w;
    if (OUTMODE == 0) {
        float4 o = make_float4(o0, o1, o2, o3);
        reinterpret_cast<float4*>(of + (size_t)row * DMODEL)[tid] = o;
    } else {
        __hip_bfloat16* p = ob + (size_t)row * DMODEL + tid * 4;
        p[0] = __float2bfloat16(o0); p[1] = __float2bfloat16(o1);
        p[2] = __float2bfloat16(o2); p[3] = __float2bfloat16(o3);
    }
}

// ---------------------------------------------------------------------------
// MFMA bf16 GEMM: C(MxN) = A(MxK) @ Wt(NxK)^T + bias
// Block 256 thr = 4 waves; block tile 64x128; wave tile 32x64 (2x4 mfma tiles)
// MODE 0: fp32 store (+ optional pos_emb[(row%196)*N+col])
// MODE 1: fp32 residual add into Cf
// MODE 2: GELU(tanh) -> bf16
// MODE 3: bf16 store
// ---------------------------------------------------------------------------
template <int MODE>
__global__ __launch_bounds__(256) void gemm_mfma(
    const __hip_bfloat16* __restrict__ A, const __hip_bfloat16* __restrict__ Wt,
    const float* __restrict__ bias, const float* __restrict__ pos,
    float* __restrict__ Cf, __hip_bfloat16* __restrict__ Cb,
    int M, int N, int K)
{
    int tid = threadIdx.x;
    int lane = tid & 63, wid = tid >> 6;
    int quad = lane >> 4, l16 = lane & 15;
    int wm = wid & 1, wn = wid >> 1;
    int r0 = blockIdx.x * 64 + wm * 32;
    int c0 = blockIdx.y * 128 + wn * 64;

    f32x4 acc[2][4];
#pragma unroll
    for (int t = 0; t < 2; ++t)
#pragma unroll
        for (int u = 0; u < 4; ++u) { f32x4 z = {0.f, 0.f, 0.f, 0.f}; acc[t][u] = z; }

    short8 zero8 = {0, 0, 0, 0, 0, 0, 0, 0};

    const short* Ap[2]; bool av[2];
#pragma unroll
    for (int t = 0; t < 2; ++t) {
        int row = r0 + t * 16 + l16;
        av[t] = row < M;
        Ap[t] = reinterpret_cast<const short*>(A) + (size_t)(av[t] ? row : 0) * K + quad * 8;
    }
    const short* Bp[4];
#pragma unroll
    for (int u = 0; u < 4; ++u) {
        int col = c0 + u * 16 + l16;
        Bp[u] = reinterpret_cast<const short*>(Wt) + (size_t)col * K + quad * 8;
    }

    for (int k = 0; k < K; k += 32) {
        short8 a[2], b[4];
#pragma unroll
        for (int t = 0; t < 2; ++t)
            a[t] = av[t] ? *reinterpret_cast<const short8*>(Ap[t] + k) : zero8;
#pragma unroll
        for (int u = 0; u < 4; ++u)
            b[u] = *reinterpret_cast<const short8*>(Bp[u] + k);
#pragma unroll
        for (int t = 0; t < 2; ++t)
#pragma unroll
            for (int u = 0; u < 4; ++u)
                acc[t][u] = __builtin_amdgcn_mfma_f32_16x16x32_bf16(a[t], b[u], acc[t][u], 0, 0, 0);
    }

    // C/D layout: col = lane&15, row = quad*4 + reg   [verified m89]
#pragma unroll
    for (int t = 0; t < 2; ++t) {
#pragma unroll
        for (int u = 0; u < 4; ++u) {
            int col = c0 + u * 16 + l16;
            float bcol = bias ? bias[col] : 0.0f;
#pragma unroll
            for (int i = 0; i < 4; ++i) {
                int row = r0 + t * 16 + quad * 4 + i;
                if (row >= M) continue;
                float val = acc[t][u][i] + bcol;
                size_t idx = (size_t)row * N + col;
                if (MODE == 0) {
                    if (pos) val += pos[(size_t)(row % LTOK) * N + col];
                    Cf[idx] = val;
                } else if (MODE == 1) {
                    Cf[idx] += val;
                } else if (MODE == 2) {
                    float u3 = val * val * val;
                    float g = 0.5f * val *
                        (1.0f + tanhf(0.7978845608028654f * (val + 0.044715f * u3)));
                    Cb[idx] = __float2bfloat16(g);
                } else {
                    Cb[idx] = __float2bfloat16(val);
                }
            }
        }
    }
}

// ---------------------------------------------------------------------------
// Attention: one block per (n, h). S=99, DH=64. fp32 math from bf16 q/k/v.
// ---------------------------------------------------------------------------
__global__ __launch_bounds__(256) void attn_kernel(
    const __hip_bfloat16* __restrict__ q, const __hip_bfloat16* __restrict__ k,
    const __hip_bfloat16* __restrict__ v, __hip_bfloat16* __restrict__ o)
{
    int n = blockIdx.x >> 4, h = blockIdx.x & 15;
    int tid = threadIdx.x, lane = tid & 63, wid = tid >> 6;
    __shared__ float ks[SEQ * 65];   // stride 65: conflict-free column reads
    __shared__ float vs[SEQ * 65];
    for (int idx = tid; idx < SEQ * DHEAD; idx += 256) {
        int s = idx >> 6, d = idx & 63;
        size_t g = ((size_t)(n * SEQ + s)) * DMODEL + h * DHEAD + d;
        ks[s * 65 + d] = __bfloat162float(k[g]);
        vs[s * 65 + d] = __bfloat162float(v[g]);
    }
    __syncthreads();
    const float scale = 0.125f;  // 1/sqrt(64)
    for (int r = wid; r < SEQ; r += 4) {
        float qreg = __bfloat162float(q[((size_t)(n * SEQ + r)) * DMODEL + h * DHEAD + lane]);
        int s2 = lane + 64;
        bool v2 = s2 < SEQ;          // lanes 0..34
        int s2i = v2 ? s2 : 0;
        float a0 = 0.f, a1 = 0.f;
#pragma unroll
        for (int d = 0; d < DHEAD; ++d) {
            float qd = __shfl(qreg, d);
            a0 += qd * ks[lane * 65 + d];
            a1 += qd * ks[s2i * 65 + d];
        }
        float sc0 = a0 * scale;
        float sc1 = v2 ? a1 * scale : -1e30f;
        float m = fmaxf(sc0, sc1);
#pragma unroll
        for (int mm = 1; mm < 64; mm <<= 1) m = fmaxf(m, __shfl_xor(m, mm));
        float e0 = __expf(sc0 - m);
        float e1 = v2 ? __expf(sc1 - m) : 0.f;
        float sum = e0 + e1;
#pragma unroll
        for (int mm = 1; mm < 64; mm <<= 1) sum += __shfl_xor(sum, mm);
        float inv = 1.0f / sum;
        float p0 = e0 * inv;   // prob for key s = lane
        float p1 = e1 * inv;   // prob for key s = lane + 64
        float accv = 0.f;
#pragma unroll 8
        for (int s = 0; s < 64; ++s) accv += __shfl(p0, s) * vs[s * 65 + lane];
#pragma unroll
        for (int s = 64; s < SEQ; ++s) accv += __shfl(p1, s - 64) * vs[s * 65 + lane];
        o[((size_t)(n * SEQ + r)) * DMODEL + h * DHEAD + lane] = __float2bfloat16(accv);
    }
}

// ---------------------------------------------------------------------------
extern "C" void kernel_launch(void* const* d_in, const int* in_sizes, int n_in,
                              void* d_out, int out_size, void* d_ws, size_t ws_size,
                              hipStream_t stream)
{
    (void)in_sizes; (void)n_in; (void)out_size; (void)ws_size;
    const float* imgs    = (const float*)d_in[0];
    const float* noise   = (const float*)d_in[1];
    const float* patch_w = (const float*)d_in[2];
    const float* patch_b = (const float*)d_in[3];
    const float* pos_emb = (const float*)d_in[4];
    const float* cls     = (const float*)d_in[5];
    const float* ln1_s   = (const float*)d_in[6];
    const float* ln1_b   = (const float*)d_in[7];
    const float* wq      = (const float*)d_in[8];
    const float* bq      = (const float*)d_in[9];
    const float* wk      = (const float*)d_in[10];
    const float* bk      = (const float*)d_in[11];
    const float* wv      = (const float*)d_in[12];
    const float* bv      = (const float*)d_in[13];
    const float* wo      = (const float*)d_in[14];
    const float* bo      = (const float*)d_in[15];
    const float* ln2_s   = (const float*)d_in[16];
    const float* ln2_b   = (const float*)d_in[17];
    const float* w1      = (const float*)d_in[18];
    const float* b1      = (const float*)d_in[19];
    const float* w2      = (const float*)d_in[20];
    const float* b2      = (const float*)d_in[21];
    const float* lnf_s   = (const float*)d_in[22];
    const float* lnf_b   = (const float*)d_in[23];

    float* out_x    = (float*)d_out;
    float* out_mask = out_x + (size_t)NS * DMODEL;

    // ---- workspace carve-up ----
    char* p = (char*)d_ws;
    auto alloc = [&](size_t bytes) {
        char* r = p; p += (bytes + 255) & ~(size_t)255; return r;
    };
    __hip_bfloat16* patch_wt = (__hip_bfloat16*)alloc((size_t)DMODEL * PDIM * 2);
    __hip_bfloat16* wqt = (__hip_bfloat16*)alloc((size_t)NLAYERS * DMODEL * DMODEL * 2);
    __hip_bfloat16* wkt = (__hip_bfloat16*)alloc((size_t)NLAYERS * DMODEL * DMODEL * 2);
    __hip_bfloat16* wvt = (__hip_bfloat16*)alloc((size_t)NLAYERS * DMODEL * DMODEL * 2);
    __hip_bfloat16* wot = (__hip_bfloat16*)alloc((size_t)NLAYERS * DMODEL * DMODEL * 2);
    __hip_bfloat16* w1t = (__hip_bfloat16*)alloc((size_t)NLAYERS * DMODEL * DMLP * 2);
    __hip_bfloat16* w2t = (__hip_bfloat16*)alloc((size_t)NLAYERS * DMODEL * DMLP * 2);
    int*   ids_keep = (int*)alloc((size_t)NIMG * NKEEP * 4);
    float* x        = (float*)alloc((size_t)NS * DMODEL * 4);
    // scratch region: layer buffers, aliased with pre-layer Apatch/x0
    char* scratch = p;
    __hip_bfloat16* ybf  = (__hip_bfloat16*)alloc((size_t)NS * DMODEL * 2);
    __hip_bfloat16* qbf  = (__hip_bfloat16*)alloc((size_t)NS * DMODEL * 2);
    __hip_bfloat16* kbf  = (__hip_bfloat16*)alloc((size_t)NS * DMODEL * 2);
    __hip_bfloat16* vbf  = (__hip_bfloat16*)alloc((size_t)NS * DMODEL * 2);
    __hip_bfloat16* obf  = (__hip_bfloat16*)alloc((size_t)NS * DMODEL * 2);
    __hip_bfloat16* h1bf = (__hip_bfloat16*)alloc((size_t)NS * DMLP * 2);
    // aliases (dead once gather_cls has run):
    __hip_bfloat16* Apatch = (__hip_bfloat16*)scratch;                       // NP*PDIM bf16
    float* x0 = (float*)(scratch + (((size_t)NP * PDIM * 2 + 255) & ~(size_t)255)); // NP*D f32

    // ---- weight conversion (every call; ws is re-poisoned) ----
    conv_transpose<<<dim3(DMODEL / 32, PDIM / 32, 1), 256, 0, stream>>>(patch_w, patch_wt, PDIM, DMODEL);
    conv_transpose<<<dim3(DMODEL / 32, DMODEL / 32, NLAYERS), 256, 0, stream>>>(wq, wqt, DMODEL, DMODEL);
    conv_transpose<<<dim3(DMODEL / 32, DMODEL / 32, NLAYERS), 256, 0, stream>>>(wk, wkt, DMODEL, DMODEL);
    conv_transpose<<<dim3(DMODEL / 32, DMODEL / 32, NLAYERS), 256, 0, stream>>>(wv, wvt, DMODEL, DMODEL);
    conv_transpose<<<dim3(DMODEL / 32, DMODEL / 32, NLAYERS), 256, 0, stream>>>(wo, wot, DMODEL, DMODEL);
    conv_transpose<<<dim3(DMLP / 32, DMODEL / 32, NLAYERS), 256, 0, stream>>>(w1, w1t, DMODEL, DMLP);
    conv_transpose<<<dim3(DMODEL / 32, DMLP / 32, NLAYERS), 256, 0, stream>>>(w2, w2t, DMLP, DMODEL);

    // ---- masking / patch embed ----
    sort_kernel<<<NIMG, 256, 0, stream>>>(noise, ids_keep, out_mask);
    patchify<<<NP, 256, 0, stream>>>(imgs, Apatch);
    gemm_mfma<0><<<dim3(NP / 64, DMODEL / 128), 256, 0, stream>>>(
        Apatch, patch_wt, patch_b, pos_emb, x0, nullptr, NP, DMODEL, PDIM);
    gather_cls<<<NS, 256, 0, stream>>>(x0, cls, ids_keep, x);

    // ---- transformer layers ----
    dim3 gD((NS + 63) / 64, DMODEL / 128);
    dim3 gM((NS + 63) / 64, DMLP / 128);
    for (int L = 0; L < NLAYERS; ++L) {
        size_t wDD = (size_t)L * DMODEL * DMODEL;
        size_t wDM = (size_t)L * DMODEL * DMLP;
        ln_kernel<1><<<NS, 256, 0, stream>>>(x, ln1_s + L * DMODEL, ln1_b + L * DMODEL, nullptr, ybf);
        gemm_mfma<3><<<gD, 256, 0, stream>>>(ybf, wqt + wDD, bq + L * DMODEL, nullptr, nullptr, qbf, NS, DMODEL, DMODEL);
        gemm_mfma<3><<<gD, 256, 0, stream>>>(ybf, wkt + wDD, bk + L * DMODEL, nullptr, nullptr, kbf, NS, DMODEL, DMODEL);
        gemm_mfma<3><<<gD, 256, 0, stream>>>(ybf, wvt + wDD, bv + L * DMODEL, nullptr, nullptr, vbf, NS, DMODEL, DMODEL);
        attn_kernel<<<NIMG * NHEADS, 256, 0, stream>>>(qbf, kbf, vbf, obf);
        gemm_mfma<1><<<gD, 256, 0, stream>>>(obf, wot + wDD, bo + L * DMODEL, nullptr, x, nullptr, NS, DMODEL, DMODEL);
        ln_kernel<1><<<NS, 256, 0, stream>>>(x, ln2_s + L * DMODEL, ln2_b + L * DMODEL, nullptr, ybf);
        gemm_mfma<2><<<gM, 256, 0, stream>>>(ybf, w1t + wDM, b1 + L * DMLP, nullptr, nullptr, h1bf, NS, DMLP, DMODEL);
        gemm_mfma<1><<<gD, 256, 0, stream>>>(h1bf, w2t + wDM, b2 + L * DMODEL, nullptr, x, nullptr, NS, DMODEL, DMLP);
    }

    // ---- final LN -> output ----
    ln_kernel<0><<<NS, 256, 0, stream>>>(x, lnf_s, lnf_b, out_x, nullptr);
}

// Round 2
// 3021.326 us; speedup vs baseline: 1.5164x; 1.5164x over previous
//
#include <hip/hip_runtime.h>
#include <hip/hip_bf16.h>
#include <math.h>

// Problem constants
#define NLAYERS 6
#define DMODEL  1024
#define NHEADS  16
#define DHEAD   64
#define DMLP    4096
#define PSZ     16
#define HWN     14
#define LTOK    196
#define NKEEP   98
#define NIMG    32
#define SEQ     99              // 1 cls + 98 kept
#define NS      (NIMG * SEQ)    // 3168
#define NP      (NIMG * LTOK)   // 6272
#define PDIM    768             // 16*16*3
#define QS      3072            // fused qkv row stride

typedef __attribute__((ext_vector_type(8))) short short8;
typedef __attribute__((ext_vector_type(4))) float f32x4;

// async global->LDS, 16B per lane. LDS dest = wave-uniform base + lane*16.
__device__ __forceinline__ void gload16(const void* g, void* l) {
    __builtin_amdgcn_global_load_lds(
        (const __attribute__((address_space(1))) void*)g,
        (__attribute__((address_space(3))) void*)l, 16, 0, 0);
}

// ---------------------------------------------------------------------------
// Weight convert + transpose: W (K x N) fp32 -> Wt (N x K) bf16, batched on z
// ---------------------------------------------------------------------------
__global__ __launch_bounds__(256) void conv_transpose(
    const float* __restrict__ W, __hip_bfloat16* __restrict__ Wt, int K, int N,
    size_t src_zs, size_t dst_zs)
{
    __shared__ float tile[32][33];
    W += (size_t)blockIdx.z * src_zs;
    Wt += (size_t)blockIdx.z * dst_zs;
    int n0 = blockIdx.x * 32, k0 = blockIdx.y * 32;
    int tx = threadIdx.x & 31, ty = threadIdx.x >> 5;  // 32 x 8
#pragma unroll
    for (int i = 0; i < 4; ++i)
        tile[ty + i * 8][tx] = W[(size_t)(k0 + ty + i * 8) * N + n0 + tx];
    __syncthreads();
#pragma unroll
    for (int i = 0; i < 4; ++i)
        Wt[(size_t)(n0 + ty + i * 8) * K + k0 + tx] = __float2bfloat16(tile[tx][ty + i * 8]);
}

// ---------------------------------------------------------------------------
// Concat q/k/v biases into (NL, 3072)
// ---------------------------------------------------------------------------
__global__ __launch_bounds__(256) void concat_bias(
    const float* __restrict__ bq, const float* __restrict__ bk,
    const float* __restrict__ bv, float* __restrict__ bqkv)
{
    int L = blockIdx.y;
    int i = blockIdx.x * 256 + threadIdx.x;   // 0..3071
    float v;
    if (i < DMODEL)            v = bq[L * DMODEL + i];
    else if (i < 2 * DMODEL)   v = bk[L * DMODEL + i - DMODEL];
    else                       v = bv[L * DMODEL + i - 2 * DMODEL];
    bqkv[(size_t)L * QS + i] = v;
}

// ---------------------------------------------------------------------------
// argsort(noise) per image via rank counting; mask written straight to d_out
// ---------------------------------------------------------------------------
__global__ __launch_bounds__(256) void sort_kernel(
    const float* __restrict__ noise, int* __restrict__ ids_keep, float* __restrict__ mask)
{
    int n = blockIdx.x, tid = threadIdx.x;
    __shared__ float nz[LTOK];
    if (tid < LTOK) nz[tid] = noise[n * LTOK + tid];
    __syncthreads();
    if (tid < LTOK) {
        float val = nz[tid];
        int rank = 0;
        for (int j = 0; j < LTOK; ++j) {
            float vj = nz[j];
            rank += (vj < val) || (vj == val && j < tid);
        }
        mask[n * LTOK + tid] = (rank < NKEEP) ? 0.0f : 1.0f;
        if (rank < NKEEP) ids_keep[n * NKEEP + rank] = tid;
    }
}

// ---------------------------------------------------------------------------
// Patchify: imgs (N,224,224,3) -> Apatch (N*196, 768) bf16
// ---------------------------------------------------------------------------
__global__ __launch_bounds__(256) void patchify(
    const float* __restrict__ imgs, __hip_bfloat16* __restrict__ Ap)
{
    int row = blockIdx.x, tid = threadIdx.x;       // 256 threads = 16x16 pixels
    int n = row / LTOK, l = row % LTOK;
    int hy = l / HWN, hx = l % HWN;
    int py = tid >> 4, px = tid & 15;
    const float* src = imgs + (((size_t)(n * 224 + hy * 16 + py)) * 224 + hx * 16 + px) * 3;
    __hip_bfloat16* dst = Ap + (size_t)row * PDIM + tid * 3;
    dst[0] = __float2bfloat16(src[0]);
    dst[1] = __float2bfloat16(src[1]);
    dst[2] = __float2bfloat16(src[2]);
}

// ---------------------------------------------------------------------------
// Gather kept tokens + prepend cls: x (NS, D) fp32
// ---------------------------------------------------------------------------
__global__ __launch_bounds__(256) void gather_cls(
    const float* __restrict__ x0, const float* __restrict__ cls,
    const int* __restrict__ ids_keep, float* __restrict__ x)
{
    int row = blockIdx.x, tid = threadIdx.x;
    int n = row / SEQ, s = row % SEQ;
    const float* src = (s == 0) ? cls
        : x0 + ((size_t)n * LTOK + ids_keep[n * NKEEP + (s - 1)]) * DMODEL;
    reinterpret_cast<float4*>(x + (size_t)row * DMODEL)[tid] =
        reinterpret_cast<const float4*>(src)[tid];
}

// ---------------------------------------------------------------------------
// LayerNorm: one block per row (D=1024, 256 thr x 4). OUTMODE 0: fp32, 1: bf16
// ---------------------------------------------------------------------------
template <int OUTMODE>
__global__ __launch_bounds__(256) void ln_kernel(
    const float* __restrict__ x, const float* __restrict__ s, const float* __restrict__ b,
    float* __restrict__ of, __hip_bfloat16* __restrict__ ob)
{
    int row = blockIdx.x, tid = threadIdx.x;
    int lane = tid & 63, wid = tid >> 6;
    float4 t = reinterpret_cast<const float4*>(x + (size_t)row * DMODEL)[tid];
    float sum = t.x + t.y + t.z + t.w;
    float sq  = t.x * t.x + t.y * t.y + t.z * t.z + t.w * t.w;
#pragma unroll
    for (int m = 1; m < 64; m <<= 1) { sum += __shfl_xor(sum, m); sq += __shfl_xor(sq, m); }
    __shared__ float sm[8];
    if (lane == 0) { sm[wid] = sum; sm[4 + wid] = sq; }
    __syncthreads();
    sum = sm[0] + sm[1] + sm[2] + sm[3];
    sq  = sm[4] + sm[5] + sm[6] + sm[7];
    float mean = sum * (1.0f / DMODEL);
    float var  = sq * (1.0f / DMODEL) - mean * mean;
    float rstd = rsqrtf(var + 1e-6f);
    float4 sv = reinterpret_cast<const float4*>(s)[tid];
    float4 bv = reinterpret_cast<const float4*>(b)[tid];
    float o0 = (t.x - mean) * rstd * sv.x + bv.x;
    float o1 = (t.y - mean) * rstd * sv.y + bv.y;
    float o2 = (t.z - mean) * rstd * sv.z + bv.z;
    float o3 = (t.w - mean) * rstd * sv.w + bv.w;
    if (OUTMODE == 0) {
        reinterpret_cast<float4*>(of + (size_t)row * DMODEL)[tid] = make_float4(o0, o1, o2, o3);
    } else {
        __hip_bfloat16* p = ob + (size_t)row * DMODEL + tid * 4;
        p[0] = __float2bfloat16(o0); p[1] = __float2bfloat16(o1);
        p[2] = __float2bfloat16(o2); p[3] = __float2bfloat16(o3);
    }
}

// ---------------------------------------------------------------------------
// MFMA bf16 GEMM, LDS-staged (m97 structure): C(MxN) = A(MxK) @ Wt(NxK)^T + bias
// Block: 256 thr = 4 waves; tile 128x128; wave tile 64x64 (4x4 mfma 16x16x32).
// K staged in BK=32 slabs via global_load_lds(16B); XOR-swizzled LDS slots.
// MODE 0: fp32 store (+ optional pos_emb[(row%196)*N+col])
// MODE 1: fp32 residual add into Cf
// MODE 2: GELU(tanh) -> bf16
// MODE 3: bf16 store
// ---------------------------------------------------------------------------
template <int MODE>
__global__ __launch_bounds__(256) void gemm_mfma(
    const __hip_bfloat16* __restrict__ A, const __hip_bfloat16* __restrict__ Wt,
    const float* __restrict__ bias, const float* __restrict__ pos,
    float* __restrict__ Cf, __hip_bfloat16* __restrict__ Cb,
    int M, int N, int K)
{
    __shared__ __hip_bfloat16 As[128 * 32];   // 8 KB, [row][slot*8..]; slot = kc ^ ((row>>1)&3)
    __shared__ __hip_bfloat16 Bs[128 * 32];   // 8 KB

    int tid = threadIdx.x;
    int lane = tid & 63, wid = tid >> 6;
    int quad = lane >> 4, l16 = lane & 15;
    int wm = wid & 1, wn = wid >> 1;
    int bm = blockIdx.x * 128, bn = blockIdx.y * 128;

    // Staging chunk indices: chunk c -> row=c>>2, LDS slot=c&3,
    // global k-chunk kc = (c&3) ^ ((c>>3)&3)  (inverse of read swizzle).
    int rowA0 = tid >> 2,        rowA1 = (tid + 256) >> 2;
    int kcA0 = (tid & 3) ^ ((tid >> 3) & 3);
    int kcA1 = (tid & 3) ^ (((tid + 256) >> 3) & 3);
    int arow0 = bm + rowA0; if (arow0 >= M) arow0 = M - 1;
    int arow1 = bm + rowA1; if (arow1 >= M) arow1 = M - 1;
    const short* Ag0 = reinterpret_cast<const short*>(A) + (size_t)arow0 * K + kcA0 * 8;
    const short* Ag1 = reinterpret_cast<const short*>(A) + (size_t)arow1 * K + kcA1 * 8;
    const short* Bg0 = reinterpret_cast<const short*>(Wt) + (size_t)(bn + rowA0) * K + kcA0 * 8;
    const short* Bg1 = reinterpret_cast<const short*>(Wt) + (size_t)(bn + rowA1) * K + kcA1 * 8;
    char* AsDst0 = (char*)As + tid * 16;
    char* AsDst1 = (char*)As + (tid + 256) * 16;
    char* BsDst0 = (char*)Bs + tid * 16;
    char* BsDst1 = (char*)Bs + (tid + 256) * 16;

    // Fragment LDS byte offsets (swizzled)
    int aOff[4], bOff[4];
#pragma unroll
    for (int t = 0; t < 4; ++t) {
        int row = wm * 64 + t * 16 + l16;
        aOff[t] = row * 64 + (quad ^ ((row >> 1) & 3)) * 16;
        int col = wn * 64 + t * 16 + l16;
        bOff[t] = col * 64 + (quad ^ ((col >> 1) & 3)) * 16;
    }

    f32x4 acc[4][4];
#pragma unroll
    for (int t = 0; t < 4; ++t)
#pragma unroll
        for (int u = 0; u < 4; ++u) { f32x4 z = {0.f, 0.f, 0.f, 0.f}; acc[t][u] = z; }

    for (int k0 = 0; k0 < K; k0 += 32) {
        gload16(Ag0 + k0, AsDst0);
        gload16(Ag1 + k0, AsDst1);
        gload16(Bg0 + k0, BsDst0);
        gload16(Bg1 + k0, BsDst1);
        __syncthreads();   // compiler emits vmcnt(0) drain before barrier

        short8 a[4], b[4];
#pragma unroll
        for (int t = 0; t < 4; ++t) a[t] = *reinterpret_cast<const short8*>((char*)As + aOff[t]);
#pragma unroll
        for (int u = 0; u < 4; ++u) b[u] = *reinterpret_cast<const short8*>((char*)Bs + bOff[u]);
#pragma unroll
        for (int t = 0; t < 4; ++t)
#pragma unroll
            for (int u = 0; u < 4; ++u)
                acc[t][u] = __builtin_amdgcn_mfma_f32_16x16x32_bf16(a[t], b[u], acc[t][u], 0, 0, 0);
        __syncthreads();   // protect LDS before next stage
    }

    // C/D layout: col = lane&15, row = quad*4 + reg   [verified m89]
#pragma unroll
    for (int t = 0; t < 4; ++t) {
#pragma unroll
        for (int u = 0; u < 4; ++u) {
            int col = bn + wn * 64 + u * 16 + l16;
            float bcol = bias ? bias[col] : 0.0f;
#pragma unroll
            for (int i = 0; i < 4; ++i) {
                int row = bm + wm * 64 + t * 16 + quad * 4 + i;
                if (row >= M) continue;
                float val = acc[t][u][i] + bcol;
                size_t idx = (size_t)row * N + col;
                if (MODE == 0) {
                    if (pos) val += pos[(size_t)(row % LTOK) * N + col];
                    Cf[idx] = val;
                } else if (MODE == 1) {
                    Cf[idx] += val;
                } else if (MODE == 2) {
                    float u3 = val * val * val;
                    float g = 0.5f * val *
                        (1.0f + tanhf(0.7978845608028654f * (val + 0.044715f * u3)));
                    Cb[idx] = __float2bfloat16(g);
                } else {
                    Cb[idx] = __float2bfloat16(val);
                }
            }
        }
    }
}

// ---------------------------------------------------------------------------
// Attention: one block per (n, h). S=99, DH=64. q/k/v rows have stride QS.
// ---------------------------------------------------------------------------
__global__ __launch_bounds__(256) void attn_kernel(
    const __hip_bfloat16* __restrict__ qkv, __hip_bfloat16* __restrict__ o)
{
    int n = blockIdx.x >> 4, h = blockIdx.x & 15;
    int tid = threadIdx.x, lane = tid & 63, wid = tid >> 6;
    const __hip_bfloat16* q = qkv;
    const __hip_bfloat16* k = qkv + DMODEL;
    const __hip_bfloat16* v = qkv + 2 * DMODEL;
    __shared__ float ks[SEQ * 65];   // stride 65: conflict-free column reads
    __shared__ float vs[SEQ * 65];
    for (int idx = tid; idx < SEQ * DHEAD; idx += 256) {
        int s = idx >> 6, d = idx & 63;
        size_t g = ((size_t)(n * SEQ + s)) * QS + h * DHEAD + d;
        ks[s * 65 + d] = __bfloat162float(k[g]);
        vs[s * 65 + d] = __bfloat162float(v[g]);
    }
    __syncthreads();
    const float scale = 0.125f;  // 1/sqrt(64)
    for (int r = wid; r < SEQ; r += 4) {
        float qreg = __bfloat162float(q[((size_t)(n * SEQ + r)) * QS + h * DHEAD + lane]);
        int s2 = lane + 64;
        bool v2 = s2 < SEQ;          // lanes 0..34
        int s2i = v2 ? s2 : 0;
        float a0 = 0.f, a1 = 0.f;
#pragma unroll
        for (int d = 0; d < DHEAD; ++d) {
            float qd = __shfl(qreg, d);
            a0 += qd * ks[lane * 65 + d];
            a1 += qd * ks[s2i * 65 + d];
        }
        float sc0 = a0 * scale;
        float sc1 = v2 ? a1 * scale : -1e30f;
        float m = fmaxf(sc0, sc1);
#pragma unroll
        for (int mm = 1; mm < 64; mm <<= 1) m = fmaxf(m, __shfl_xor(m, mm));
        float e0 = __expf(sc0 - m);
        float e1 = v2 ? __expf(sc1 - m) : 0.f;
        float sum = e0 + e1;
#pragma unroll
        for (int mm = 1; mm < 64; mm <<= 1) sum += __shfl_xor(sum, mm);
        float inv = 1.0f / sum;
        float p0 = e0 * inv;
        float p1 = e1 * inv;
        float accv = 0.f;
#pragma unroll 8
        for (int s = 0; s < 64; ++s) accv += __shfl(p0, s) * vs[s * 65 + lane];
#pragma unroll
        for (int s = 64; s < SEQ; ++s) accv += __shfl(p1, s - 64) * vs[s * 65 + lane];
        o[((size_t)(n * SEQ + r)) * DMODEL + h * DHEAD + lane] = __float2bfloat16(accv);
    }
}

// ---------------------------------------------------------------------------
extern "C" void kernel_launch(void* const* d_in, const int* in_sizes, int n_in,
                              void* d_out, int out_size, void* d_ws, size_t ws_size,
                              hipStream_t stream)
{
    (void)in_sizes; (void)n_in; (void)out_size; (void)ws_size;
    const float* imgs    = (const float*)d_in[0];
    const float* noise   = (const float*)d_in[1];
    const float* patch_w = (const float*)d_in[2];
    const float* patch_b = (const float*)d_in[3];
    const float* pos_emb = (const float*)d_in[4];
    const float* cls     = (const float*)d_in[5];
    const float* ln1_s   = (const float*)d_in[6];
    const float* ln1_b   = (const float*)d_in[7];
    const float* wq      = (const float*)d_in[8];
    const float* bq      = (const float*)d_in[9];
    const float* wk      = (const float*)d_in[10];
    const float* bk      = (const float*)d_in[11];
    const float* wv      = (const float*)d_in[12];
    const float* bv      = (const float*)d_in[13];
    const float* wo      = (const float*)d_in[14];
    const float* bo      = (const float*)d_in[15];
    const float* ln2_s   = (const float*)d_in[16];
    const float* ln2_b   = (const float*)d_in[17];
    const float* w1      = (const float*)d_in[18];
    const float* b1      = (const float*)d_in[19];
    const float* w2      = (const float*)d_in[20];
    const float* b2      = (const float*)d_in[21];
    const float* lnf_s   = (const float*)d_in[22];
    const float* lnf_b   = (const float*)d_in[23];

    float* out_x    = (float*)d_out;
    float* out_mask = out_x + (size_t)NS * DMODEL;

    // ---- workspace carve-up ----
    char* p = (char*)d_ws;
    auto alloc = [&](size_t bytes) {
        char* r = p; p += (bytes + 255) & ~(size_t)255; return r;
    };
    __hip_bfloat16* patch_wt = (__hip_bfloat16*)alloc((size_t)DMODEL * PDIM * 2);
    __hip_bfloat16* wqkvt    = (__hip_bfloat16*)alloc((size_t)NLAYERS * QS * DMODEL * 2);
    __hip_bfloat16* wot = (__hip_bfloat16*)alloc((size_t)NLAYERS * DMODEL * DMODEL * 2);
    __hip_bfloat16* w1t = (__hip_bfloat16*)alloc((size_t)NLAYERS * DMODEL * DMLP * 2);
    __hip_bfloat16* w2t = (__hip_bfloat16*)alloc((size_t)NLAYERS * DMODEL * DMLP * 2);
    float* bqkv     = (float*)alloc((size_t)NLAYERS * QS * 4);
    int*   ids_keep = (int*)alloc((size_t)NIMG * NKEEP * 4);
    float* x        = (float*)alloc((size_t)NS * DMODEL * 4);
    // scratch region: layer buffers, aliased with pre-layer Apatch/x0
    char* scratch = p;
    __hip_bfloat16* ybf  = (__hip_bfloat16*)alloc((size_t)NS * DMODEL * 2);
    __hip_bfloat16* qkv  = (__hip_bfloat16*)alloc((size_t)NS * QS * 2);
    __hip_bfloat16* obf  = (__hip_bfloat16*)alloc((size_t)NS * DMODEL * 2);
    __hip_bfloat16* h1bf = (__hip_bfloat16*)alloc((size_t)NS * DMLP * 2);
    // aliases (dead once gather_cls has run):
    __hip_bfloat16* Apatch = (__hip_bfloat16*)scratch;                       // NP*PDIM bf16
    float* x0 = (float*)(scratch + (((size_t)NP * PDIM * 2 + 255) & ~(size_t)255)); // NP*D f32

    const size_t DD = (size_t)DMODEL * DMODEL;
    const size_t DM = (size_t)DMODEL * DMLP;

    // ---- weight conversion (every call; ws is re-poisoned) ----
    conv_transpose<<<dim3(DMODEL / 32, PDIM / 32, 1), 256, 0, stream>>>(
        patch_w, patch_wt, PDIM, DMODEL, PDIM * DMODEL, PDIM * DMODEL);
    conv_transpose<<<dim3(DMODEL / 32, DMODEL / 32, NLAYERS), 256, 0, stream>>>(
        wq, wqkvt, DMODEL, DMODEL, DD, (size_t)QS * DMODEL);
    conv_transpose<<<dim3(DMODEL / 32, DMODEL / 32, NLAYERS), 256, 0, stream>>>(
        wk, wqkvt + DD, DMODEL, DMODEL, DD, (size_t)QS * DMODEL);
    conv_transpose<<<dim3(DMODEL / 32, DMODEL / 32, NLAYERS), 256, 0, stream>>>(
        wv, wqkvt + 2 * DD, DMODEL, DMODEL, DD, (size_t)QS * DMODEL);
    conv_transpose<<<dim3(DMODEL / 32, DMODEL / 32, NLAYERS), 256, 0, stream>>>(
        wo, wot, DMODEL, DMODEL, DD, DD);
    conv_transpose<<<dim3(DMLP / 32, DMODEL / 32, NLAYERS), 256, 0, stream>>>(
        w1, w1t, DMODEL, DMLP, DM, DM);
    conv_transpose<<<dim3(DMODEL / 32, DMLP / 32, NLAYERS), 256, 0, stream>>>(
        w2, w2t, DMLP, DMODEL, DM, DM);
    concat_bias<<<dim3(QS / 256, NLAYERS), 256, 0, stream>>>(bq, bk, bv, bqkv);

    // ---- masking / patch embed ----
    sort_kernel<<<NIMG, 256, 0, stream>>>(noise, ids_keep, out_mask);
    patchify<<<NP, 256, 0, stream>>>(imgs, Apatch);
    gemm_mfma<0><<<dim3(NP / 128, DMODEL / 128), 256, 0, stream>>>(
        Apatch, patch_wt, patch_b, pos_emb, x0, nullptr, NP, DMODEL, PDIM);
    gather_cls<<<NS, 256, 0, stream>>>(x0, cls, ids_keep, x);

    // ---- transformer layers ----
    dim3 gQKV((NS + 127) / 128, QS / 128);
    dim3 gD((NS + 127) / 128, DMODEL / 128);
    dim3 gM((NS + 127) / 128, DMLP / 128);
    for (int L = 0; L < NLAYERS; ++L) {
        size_t wDD = (size_t)L * DD;
        size_t wDM = (size_t)L * DM;
        ln_kernel<1><<<NS, 256, 0, stream>>>(x, ln1_s + L * DMODEL, ln1_b + L * DMODEL, nullptr, ybf);
        gemm_mfma<3><<<gQKV, 256, 0, stream>>>(ybf, wqkvt + (size_t)L * QS * DMODEL,
                                               bqkv + (size_t)L * QS, nullptr, nullptr, qkv,
                                               NS, QS, DMODEL);
        attn_kernel<<<NIMG * NHEADS, 256, 0, stream>>>(qkv, obf);
        gemm_mfma<1><<<gD, 256, 0, stream>>>(obf, wot + wDD, bo + L * DMODEL, nullptr, x, nullptr, NS, DMODEL, DMODEL);
        ln_kernel<1><<<NS, 256, 0, stream>>>(x, ln2_s + L * DMODEL, ln2_b + L * DMODEL, nullptr, ybf);
        gemm_mfma<2><<<gM, 256, 0, stream>>>(ybf, w1t + wDM, b1 + L * DMLP, nullptr, nullptr, h1bf, NS, DMLP, DMODEL);
        gemm_mfma<1><<<gD, 256, 0, stream>>>(h1bf, w2t + wDM, b2 + L * DMODEL, nullptr, x, nullptr, NS, DMODEL, DMLP);
    }

    // ---- final LN -> output ----
    ln_kernel<0><<<NS, 256, 0, stream>>>(x, lnf_s, lnf_b, out_x, nullptr);
}

// Round 3
// 2266.156 us; speedup vs baseline: 2.0217x; 1.3332x over previous
//
#include <hip/hip_runtime.h>
#include <hip/hip_bf16.h>
#include <math.h>

// Problem constants
#define NLAYERS 6
#define DMODEL  1024
#define NHEADS  16
#define DHEAD   64
#define DMLP    4096
#define PSZ     16
#define HWN     14
#define LTOK    196
#define NKEEP   98
#define NIMG    32
#define SEQ     99              // 1 cls + 98 kept
#define NS      (NIMG * SEQ)    // 3168
#define NP      (NIMG * LTOK)   // 6272
#define PDIM    768             // 16*16*3
#define QS      3072            // fused qkv row stride
#define SPAD    112             // seq padded to 7*16
#define VT_PITCH 136            // Vt row pitch (bf16 elems); 272B = 4 banks offset/row
#define P_PITCH  136            // P row pitch

typedef __attribute__((ext_vector_type(8))) short short8;
typedef __attribute__((ext_vector_type(4))) float f32x4;

// async global->LDS, 16B per lane. LDS dest = wave-uniform base + lane*16.
__device__ __forceinline__ void gload16(const void* g, void* l) {
    __builtin_amdgcn_global_load_lds(
        (const __attribute__((address_space(1))) void*)g,
        (__attribute__((address_space(3))) void*)l, 16, 0, 0);
}

// ---------------------------------------------------------------------------
// Weight convert + transpose: W (K x N) fp32 -> Wt (N x K) bf16, batched on z
// ---------------------------------------------------------------------------
__global__ __launch_bounds__(256) void conv_transpose(
    const float* __restrict__ W, __hip_bfloat16* __restrict__ Wt, int K, int N,
    size_t src_zs, size_t dst_zs)
{
    __shared__ float tile[32][33];
    W += (size_t)blockIdx.z * src_zs;
    Wt += (size_t)blockIdx.z * dst_zs;
    int n0 = blockIdx.x * 32, k0 = blockIdx.y * 32;
    int tx = threadIdx.x & 31, ty = threadIdx.x >> 5;  // 32 x 8
#pragma unroll
    for (int i = 0; i < 4; ++i)
        tile[ty + i * 8][tx] = W[(size_t)(k0 + ty + i * 8) * N + n0 + tx];
    __syncthreads();
#pragma unroll
    for (int i = 0; i < 4; ++i)
        Wt[(size_t)(n0 + ty + i * 8) * K + k0 + tx] = __float2bfloat16(tile[tx][ty + i * 8]);
}

// ---------------------------------------------------------------------------
// Concat q/k/v biases into (NL, 3072)
// ---------------------------------------------------------------------------
__global__ __launch_bounds__(256) void concat_bias(
    const float* __restrict__ bq, const float* __restrict__ bk,
    const float* __restrict__ bv, float* __restrict__ bqkv)
{
    int L = blockIdx.y;
    int i = blockIdx.x * 256 + threadIdx.x;   // 0..3071
    float v;
    if (i < DMODEL)            v = bq[L * DMODEL + i];
    else if (i < 2 * DMODEL)   v = bk[L * DMODEL + i - DMODEL];
    else                       v = bv[L * DMODEL + i - 2 * DMODEL];
    bqkv[(size_t)L * QS + i] = v;
}

// ---------------------------------------------------------------------------
// argsort(noise) per image via rank counting; mask written straight to d_out
// ---------------------------------------------------------------------------
__global__ __launch_bounds__(256) void sort_kernel(
    const float* __restrict__ noise, int* __restrict__ ids_keep, float* __restrict__ mask)
{
    int n = blockIdx.x, tid = threadIdx.x;
    __shared__ float nz[LTOK];
    if (tid < LTOK) nz[tid] = noise[n * LTOK + tid];
    __syncthreads();
    if (tid < LTOK) {
        float val = nz[tid];
        int rank = 0;
        for (int j = 0; j < LTOK; ++j) {
            float vj = nz[j];
            rank += (vj < val) || (vj == val && j < tid);
        }
        mask[n * LTOK + tid] = (rank < NKEEP) ? 0.0f : 1.0f;
        if (rank < NKEEP) ids_keep[n * NKEEP + rank] = tid;
    }
}

// ---------------------------------------------------------------------------
// Patchify: imgs (N,224,224,3) -> Apatch (N*196, 768) bf16
// ---------------------------------------------------------------------------
__global__ __launch_bounds__(256) void patchify(
    const float* __restrict__ imgs, __hip_bfloat16* __restrict__ Ap)
{
    int row = blockIdx.x, tid = threadIdx.x;       // 256 threads = 16x16 pixels
    int n = row / LTOK, l = row % LTOK;
    int hy = l / HWN, hx = l % HWN;
    int py = tid >> 4, px = tid & 15;
    const float* src = imgs + (((size_t)(n * 224 + hy * 16 + py)) * 224 + hx * 16 + px) * 3;
    __hip_bfloat16* dst = Ap + (size_t)row * PDIM + tid * 3;
    dst[0] = __float2bfloat16(src[0]);
    dst[1] = __float2bfloat16(src[1]);
    dst[2] = __float2bfloat16(src[2]);
}

// ---------------------------------------------------------------------------
// Gather kept tokens + prepend cls: x (NS, D) fp32
// ---------------------------------------------------------------------------
__global__ __launch_bounds__(256) void gather_cls(
    const float* __restrict__ x0, const float* __restrict__ cls,
    const int* __restrict__ ids_keep, float* __restrict__ x)
{
    int row = blockIdx.x, tid = threadIdx.x;
    int n = row / SEQ, s = row % SEQ;
    const float* src = (s == 0) ? cls
        : x0 + ((size_t)n * LTOK + ids_keep[n * NKEEP + (s - 1)]) * DMODEL;
    reinterpret_cast<float4*>(x + (size_t)row * DMODEL)[tid] =
        reinterpret_cast<const float4*>(src)[tid];
}

// ---------------------------------------------------------------------------
// LayerNorm: one block per row (D=1024, 256 thr x 4). OUTMODE 0: fp32, 1: bf16
// ---------------------------------------------------------------------------
template <int OUTMODE>
__global__ __launch_bounds__(256) void ln_kernel(
    const float* __restrict__ x, const float* __restrict__ s, const float* __restrict__ b,
    float* __restrict__ of, __hip_bfloat16* __restrict__ ob)
{
    int row = blockIdx.x, tid = threadIdx.x;
    int lane = tid & 63, wid = tid >> 6;
    float4 t = reinterpret_cast<const float4*>(x + (size_t)row * DMODEL)[tid];
    float sum = t.x + t.y + t.z + t.w;
    float sq  = t.x * t.x + t.y * t.y + t.z * t.z + t.w * t.w;
#pragma unroll
    for (int m = 1; m < 64; m <<= 1) { sum += __shfl_xor(sum, m); sq += __shfl_xor(sq, m); }
    __shared__ float sm[8];
    if (lane == 0) { sm[wid] = sum; sm[4 + wid] = sq; }
    __syncthreads();
    sum = sm[0] + sm[1] + sm[2] + sm[3];
    sq  = sm[4] + sm[5] + sm[6] + sm[7];
    float mean = sum * (1.0f / DMODEL);
    float var  = sq * (1.0f / DMODEL) - mean * mean;
    float rstd = rsqrtf(var + 1e-6f);
    float4 sv = reinterpret_cast<const float4*>(s)[tid];
    float4 bv = reinterpret_cast<const float4*>(b)[tid];
    float o0 = (t.x - mean) * rstd * sv.x + bv.x;
    float o1 = (t.y - mean) * rstd * sv.y + bv.y;
    float o2 = (t.z - mean) * rstd * sv.z + bv.z;
    float o3 = (t.w - mean) * rstd * sv.w + bv.w;
    if (OUTMODE == 0) {
        reinterpret_cast<float4*>(of + (size_t)row * DMODEL)[tid] = make_float4(o0, o1, o2, o3);
    } else {
        __hip_bfloat16* p = ob + (size_t)row * DMODEL + tid * 4;
        p[0] = __float2bfloat16(o0); p[1] = __float2bfloat16(o1);
        p[2] = __float2bfloat16(o2); p[3] = __float2bfloat16(o3);
    }
}

// ---------------------------------------------------------------------------
// MFMA bf16 GEMM, LDS-staged (m97 structure): C(MxN) = A(MxK) @ Wt(NxK)^T + bias
// ---------------------------------------------------------------------------
template <int MODE>
__global__ __launch_bounds__(256) void gemm_mfma(
    const __hip_bfloat16* __restrict__ A, const __hip_bfloat16* __restrict__ Wt,
    const float* __restrict__ bias, const float* __restrict__ pos,
    float* __restrict__ Cf, __hip_bfloat16* __restrict__ Cb,
    int M, int N, int K)
{
    __shared__ __hip_bfloat16 As[128 * 32];   // 8 KB; slot = kc ^ ((row>>1)&3)
    __shared__ __hip_bfloat16 Bs[128 * 32];   // 8 KB

    int tid = threadIdx.x;
    int lane = tid & 63, wid = tid >> 6;
    int quad = lane >> 4, l16 = lane & 15;
    int wm = wid & 1, wn = wid >> 1;
    int bm = blockIdx.x * 128, bn = blockIdx.y * 128;

    int rowA0 = tid >> 2,        rowA1 = (tid + 256) >> 2;
    int kcA0 = (tid & 3) ^ ((tid >> 3) & 3);
    int kcA1 = (tid & 3) ^ (((tid + 256) >> 3) & 3);
    int arow0 = bm + rowA0; if (arow0 >= M) arow0 = M - 1;
    int arow1 = bm + rowA1; if (arow1 >= M) arow1 = M - 1;
    const short* Ag0 = reinterpret_cast<const short*>(A) + (size_t)arow0 * K + kcA0 * 8;
    const short* Ag1 = reinterpret_cast<const short*>(A) + (size_t)arow1 * K + kcA1 * 8;
    const short* Bg0 = reinterpret_cast<const short*>(Wt) + (size_t)(bn + rowA0) * K + kcA0 * 8;
    const short* Bg1 = reinterpret_cast<const short*>(Wt) + (size_t)(bn + rowA1) * K + kcA1 * 8;
    char* AsDst0 = (char*)As + tid * 16;
    char* AsDst1 = (char*)As + (tid + 256) * 16;
    char* BsDst0 = (char*)Bs + tid * 16;
    char* BsDst1 = (char*)Bs + (tid + 256) * 16;

    int aOff[4], bOff[4];
#pragma unroll
    for (int t = 0; t < 4; ++t) {
        int row = wm * 64 + t * 16 + l16;
        aOff[t] = row * 64 + (quad ^ ((row >> 1) & 3)) * 16;
        int col = wn * 64 + t * 16 + l16;
        bOff[t] = col * 64 + (quad ^ ((col >> 1) & 3)) * 16;
    }

    f32x4 acc[4][4];
#pragma unroll
    for (int t = 0; t < 4; ++t)
#pragma unroll
        for (int u = 0; u < 4; ++u) { f32x4 z = {0.f, 0.f, 0.f, 0.f}; acc[t][u] = z; }

    for (int k0 = 0; k0 < K; k0 += 32) {
        gload16(Ag0 + k0, AsDst0);
        gload16(Ag1 + k0, AsDst1);
        gload16(Bg0 + k0, BsDst0);
        gload16(Bg1 + k0, BsDst1);
        __syncthreads();

        short8 a[4], b[4];
#pragma unroll
        for (int t = 0; t < 4; ++t) a[t] = *reinterpret_cast<const short8*>((char*)As + aOff[t]);
#pragma unroll
        for (int u = 0; u < 4; ++u) b[u] = *reinterpret_cast<const short8*>((char*)Bs + bOff[u]);
#pragma unroll
        for (int t = 0; t < 4; ++t)
#pragma unroll
            for (int u = 0; u < 4; ++u)
                acc[t][u] = __builtin_amdgcn_mfma_f32_16x16x32_bf16(a[t], b[u], acc[t][u], 0, 0, 0);
        __syncthreads();
    }

    // C/D layout: col = lane&15, row = quad*4 + reg   [verified m89]
#pragma unroll
    for (int t = 0; t < 4; ++t) {
#pragma unroll
        for (int u = 0; u < 4; ++u) {
            int col = bn + wn * 64 + u * 16 + l16;
            float bcol = bias ? bias[col] : 0.0f;
#pragma unroll
            for (int i = 0; i < 4; ++i) {
                int row = bm + wm * 64 + t * 16 + quad * 4 + i;
                if (row >= M) continue;
                float val = acc[t][u][i] + bcol;
                size_t idx = (size_t)row * N + col;
                if (MODE == 0) {
                    if (pos) val += pos[(size_t)(row % LTOK) * N + col];
                    Cf[idx] = val;
                } else if (MODE == 1) {
                    Cf[idx] += val;
                } else if (MODE == 2) {
                    float u3 = val * val * val;
                    float g = 0.5f * val *
                        (1.0f + tanhf(0.7978845608028654f * (val + 0.044715f * u3)));
                    Cb[idx] = __float2bfloat16(g);
                } else {
                    Cb[idx] = __float2bfloat16(val);
                }
            }
        }
    }
}

// ---------------------------------------------------------------------------
// MFMA attention: one block per (n, h); 4 waves, each owns Q-tiles qt, qt+4.
// S=99 padded to 112 (7 key tiles of 16). q/k fragments loaded directly from
// global (16B contiguous); V transposed into LDS once; P via wave-private LDS.
// ---------------------------------------------------------------------------
__global__ __launch_bounds__(256) void attn_mfma(
    const __hip_bfloat16* __restrict__ qkv, __hip_bfloat16* __restrict__ o)
{
    int n = blockIdx.x >> 4, h = blockIdx.x & 15;
    int tid = threadIdx.x, lane = tid & 63, wid = tid >> 6;
    int quad = lane >> 4, l16 = lane & 15;

    __shared__ __hip_bfloat16 Vt[DHEAD * VT_PITCH];      // [d][key] 17408 B
    __shared__ __hip_bfloat16 Ps[4][16 * P_PITCH];       // wave-private P, 17408 B

    // zero Vt (pad keys >= 99 must be 0) and Ps (pad cols 112.. must be 0)
    {
        int4 zz = make_int4(0, 0, 0, 0);
        int4* v4 = (int4*)Vt;
        int4* p4 = (int4*)Ps;
        for (int i = tid; i < (DHEAD * VT_PITCH) / 8; i += 256) v4[i] = zz;
        for (int i = tid; i < (4 * 16 * P_PITCH) / 8; i += 256) p4[i] = zz;
    }
    __syncthreads();
    // stage V transposed: Vt[d][s] = v[s][d]
    for (int idx = tid; idx < SEQ * DHEAD; idx += 256) {
        int s = idx >> 6, d = idx & 63;
        Vt[d * VT_PITCH + s] = qkv[((size_t)(n * SEQ + s)) * QS + 2 * DMODEL + h * DHEAD + d];
    }
    __syncthreads();

    const short* qbase = reinterpret_cast<const short*>(qkv) + (size_t)n * SEQ * QS + h * DHEAD;
    const short* kbase = qbase + DMODEL;
    const float scale = 0.125f;  // 1/sqrt(64)

    for (int qt = wid; qt < 7; qt += 4) {
        int q0 = qt * 16;
        // A-fragments of Q: lane m=l16 -> row q0+l16, k = c*32 + quad*8
        int qrow = q0 + l16; if (qrow >= SEQ) qrow = SEQ - 1;
        const short* qp = qbase + (size_t)qrow * QS + quad * 8;
        short8 aq0 = *reinterpret_cast<const short8*>(qp);
        short8 aq1 = *reinterpret_cast<const short8*>(qp + 32);

        // QK^T: scores sc[u] for key tile u (C-layout: row=quad*4+i, col=l16)
        f32x4 sc[7];
#pragma unroll
        for (int u = 0; u < 7; ++u) {
            int krow = u * 16 + l16; if (krow >= SEQ) krow = SEQ - 1;
            const short* kp = kbase + (size_t)krow * QS + quad * 8;
            short8 kb0 = *reinterpret_cast<const short8*>(kp);
            short8 kb1 = *reinterpret_cast<const short8*>(kp + 32);
            f32x4 s = {0.f, 0.f, 0.f, 0.f};
            s = __builtin_amdgcn_mfma_f32_16x16x32_bf16(aq0, kb0, s, 0, 0, 0);
            s = __builtin_amdgcn_mfma_f32_16x16x32_bf16(aq1, kb1, s, 0, 0, 0);
            sc[u] = s;
        }
        // scale + mask keys >= 99 (only tile u=6: keys 96..111 -> l16 >= 3)
#pragma unroll
        for (int u = 0; u < 7; ++u)
#pragma unroll
            for (int i = 0; i < 4; ++i)
                sc[u][i] *= scale;
        if (l16 >= 3) {
#pragma unroll
            for (int i = 0; i < 4; ++i) sc[6][i] = -1e30f;
        }
        // row softmax (row = quad*4+i spans 16 lanes l16 x 7 tiles)
#pragma unroll
        for (int i = 0; i < 4; ++i) {
            float m = sc[0][i];
#pragma unroll
            for (int u = 1; u < 7; ++u) m = fmaxf(m, sc[u][i]);
            m = fmaxf(m, __shfl_xor(m, 1));
            m = fmaxf(m, __shfl_xor(m, 2));
            m = fmaxf(m, __shfl_xor(m, 4));
            m = fmaxf(m, __shfl_xor(m, 8));
            float sum = 0.f;
#pragma unroll
            for (int u = 0; u < 7; ++u) {
                float e = __expf(sc[u][i] - m);
                sc[u][i] = e;
                sum += e;
            }
            sum += __shfl_xor(sum, 1);
            sum += __shfl_xor(sum, 2);
            sum += __shfl_xor(sum, 4);
            sum += __shfl_xor(sum, 8);
            float inv = 1.0f / sum;
            // write P row (C-layout -> LDS), cols 112..135 stay zero
            __hip_bfloat16* pr = &Ps[wid][(quad * 4 + i) * P_PITCH];
#pragma unroll
            for (int u = 0; u < 7; ++u)
                pr[u * 16 + l16] = __float2bfloat16(sc[u][i] * inv);
        }
        // PV: A = P (A-layout: lane m=l16 -> row l16, k = kc*32+quad*8)
        short8 ap[4];
#pragma unroll
        for (int kc = 0; kc < 4; ++kc)
            ap[kc] = *reinterpret_cast<const short8*>(&Ps[wid][l16 * P_PITCH + kc * 32 + quad * 8]);
        f32x4 oacc[4];
#pragma unroll
        for (int dt = 0; dt < 4; ++dt) { f32x4 z = {0.f, 0.f, 0.f, 0.f}; oacc[dt] = z; }
#pragma unroll
        for (int kc = 0; kc < 4; ++kc) {
#pragma unroll
            for (int dt = 0; dt < 4; ++dt) {
                short8 vb = *reinterpret_cast<const short8*>(
                    &Vt[(dt * 16 + l16) * VT_PITCH + kc * 32 + quad * 8]);
                oacc[dt] = __builtin_amdgcn_mfma_f32_16x16x32_bf16(ap[kc], vb, oacc[dt], 0, 0, 0);
            }
        }
        // store O (C-layout): row q0+quad*4+i, col = h*64 + dt*16+l16
#pragma unroll
        for (int dt = 0; dt < 4; ++dt) {
#pragma unroll
            for (int i = 0; i < 4; ++i) {
                int row = q0 + quad * 4 + i;
                if (row < SEQ)
                    o[((size_t)(n * SEQ + row)) * DMODEL + h * DHEAD + dt * 16 + l16] =
                        __float2bfloat16(oacc[dt][i]);
            }
        }
    }
}

// ---------------------------------------------------------------------------
extern "C" void kernel_launch(void* const* d_in, const int* in_sizes, int n_in,
                              void* d_out, int out_size, void* d_ws, size_t ws_size,
                              hipStream_t stream)
{
    (void)in_sizes; (void)n_in; (void)out_size; (void)ws_size;
    const float* imgs    = (const float*)d_in[0];
    const float* noise   = (const float*)d_in[1];
    const float* patch_w = (const float*)d_in[2];
    const float* patch_b = (const float*)d_in[3];
    const float* pos_emb = (const float*)d_in[4];
    const float* cls     = (const float*)d_in[5];
    const float* ln1_s   = (const float*)d_in[6];
    const float* ln1_b   = (const float*)d_in[7];
    const float* wq      = (const float*)d_in[8];
    const float* bq      = (const float*)d_in[9];
    const float* wk      = (const float*)d_in[10];
    const float* bk      = (const float*)d_in[11];
    const float* wv      = (const float*)d_in[12];
    const float* bv      = (const float*)d_in[13];
    const float* wo      = (const float*)d_in[14];
    const float* bo      = (const float*)d_in[15];
    const float* ln2_s   = (const float*)d_in[16];
    const float* ln2_b   = (const float*)d_in[17];
    const float* w1      = (const float*)d_in[18];
    const float* b1      = (const float*)d_in[19];
    const float* w2      = (const float*)d_in[20];
    const float* b2      = (const float*)d_in[21];
    const float* lnf_s   = (const float*)d_in[22];
    const float* lnf_b   = (const float*)d_in[23];

    float* out_x    = (float*)d_out;
    float* out_mask = out_x + (size_t)NS * DMODEL;

    // ---- workspace carve-up ----
    char* p = (char*)d_ws;
    auto alloc = [&](size_t bytes) {
        char* r = p; p += (bytes + 255) & ~(size_t)255; return r;
    };
    __hip_bfloat16* patch_wt = (__hip_bfloat16*)alloc((size_t)DMODEL * PDIM * 2);
    __hip_bfloat16* wqkvt    = (__hip_bfloat16*)alloc((size_t)NLAYERS * QS * DMODEL * 2);
    __hip_bfloat16* wot = (__hip_bfloat16*)alloc((size_t)NLAYERS * DMODEL * DMODEL * 2);
    __hip_bfloat16* w1t = (__hip_bfloat16*)alloc((size_t)NLAYERS * DMODEL * DMLP * 2);
    __hip_bfloat16* w2t = (__hip_bfloat16*)alloc((size_t)NLAYERS * DMODEL * DMLP * 2);
    float* bqkv     = (float*)alloc((size_t)NLAYERS * QS * 4);
    int*   ids_keep = (int*)alloc((size_t)NIMG * NKEEP * 4);
    float* x        = (float*)alloc((size_t)NS * DMODEL * 4);
    // scratch region: layer buffers, aliased with pre-layer Apatch/x0
    char* scratch = p;
    __hip_bfloat16* ybf  = (__hip_bfloat16*)alloc((size_t)NS * DMODEL * 2);
    __hip_bfloat16* qkv  = (__hip_bfloat16*)alloc((size_t)NS * QS * 2);
    __hip_bfloat16* obf  = (__hip_bfloat16*)alloc((size_t)NS * DMODEL * 2);
    __hip_bfloat16* h1bf = (__hip_bfloat16*)alloc((size_t)NS * DMLP * 2);
    // aliases (dead once gather_cls has run):
    __hip_bfloat16* Apatch = (__hip_bfloat16*)scratch;                       // NP*PDIM bf16
    float* x0 = (float*)(scratch + (((size_t)NP * PDIM * 2 + 255) & ~(size_t)255)); // NP*D f32

    const size_t DD = (size_t)DMODEL * DMODEL;
    const size_t DM = (size_t)DMODEL * DMLP;

    // ---- weight conversion (every call; ws is re-poisoned) ----
    conv_transpose<<<dim3(DMODEL / 32, PDIM / 32, 1), 256, 0, stream>>>(
        patch_w, patch_wt, PDIM, DMODEL, PDIM * DMODEL, PDIM * DMODEL);
    conv_transpose<<<dim3(DMODEL / 32, DMODEL / 32, NLAYERS), 256, 0, stream>>>(
        wq, wqkvt, DMODEL, DMODEL, DD, (size_t)QS * DMODEL);
    conv_transpose<<<dim3(DMODEL / 32, DMODEL / 32, NLAYERS), 256, 0, stream>>>(
        wk, wqkvt + DD, DMODEL, DMODEL, DD, (size_t)QS * DMODEL);
    conv_transpose<<<dim3(DMODEL / 32, DMODEL / 32, NLAYERS), 256, 0, stream>>>(
        wv, wqkvt + 2 * DD, DMODEL, DMODEL, DD, (size_t)QS * DMODEL);
    conv_transpose<<<dim3(DMODEL / 32, DMODEL / 32, NLAYERS), 256, 0, stream>>>(
        wo, wot, DMODEL, DMODEL, DD, DD);
    conv_transpose<<<dim3(DMLP / 32, DMODEL / 32, NLAYERS), 256, 0, stream>>>(
        w1, w1t, DMODEL, DMLP, DM, DM);
    conv_transpose<<<dim3(DMODEL / 32, DMLP / 32, NLAYERS), 256, 0, stream>>>(
        w2, w2t, DMLP, DMODEL, DM, DM);
    concat_bias<<<dim3(QS / 256, NLAYERS), 256, 0, stream>>>(bq, bk, bv, bqkv);

    // ---- masking / patch embed ----
    sort_kernel<<<NIMG, 256, 0, stream>>>(noise, ids_keep, out_mask);
    patchify<<<NP, 256, 0, stream>>>(imgs, Apatch);
    gemm_mfma<0><<<dim3(NP / 128, DMODEL / 128), 256, 0, stream>>>(
        Apatch, patch_wt, patch_b, pos_emb, x0, nullptr, NP, DMODEL, PDIM);
    gather_cls<<<NS, 256, 0, stream>>>(x0, cls, ids_keep, x);

    // ---- transformer layers ----
    dim3 gQKV((NS + 127) / 128, QS / 128);
    dim3 gD((NS + 127) / 128, DMODEL / 128);
    dim3 gM((NS + 127) / 128, DMLP / 128);
    for (int L = 0; L < NLAYERS; ++L) {
        size_t wDD = (size_t)L * DD;
        size_t wDM = (size_t)L * DM;
        ln_kernel<1><<<NS, 256, 0, stream>>>(x, ln1_s + L * DMODEL, ln1_b + L * DMODEL, nullptr, ybf);
        gemm_mfma<3><<<gQKV, 256, 0, stream>>>(ybf, wqkvt + (size_t)L * QS * DMODEL,
                                               bqkv + (size_t)L * QS, nullptr, nullptr, qkv,
                                               NS, QS, DMODEL);
        attn_mfma<<<NIMG * NHEADS, 256, 0, stream>>>(qkv, obf);
        gemm_mfma<1><<<gD, 256, 0, stream>>>(obf, wot + wDD, bo + L * DMODEL, nullptr, x, nullptr, NS, DMODEL, DMODEL);
        ln_kernel<1><<<NS, 256, 0, stream>>>(x, ln2_s + L * DMODEL, ln2_b + L * DMODEL, nullptr, ybf);
        gemm_mfma<2><<<gM, 256, 0, stream>>>(ybf, w1t + wDM, b1 + L * DMLP, nullptr, nullptr, h1bf, NS, DMLP, DMODEL);
        gemm_mfma<1><<<gD, 256, 0, stream>>>(h1bf, w2t + wDM, b2 + L * DMODEL, nullptr, x, nullptr, NS, DMODEL, DMLP);
    }

    // ---- final LN -> output ----
    ln_kernel<0><<<NS, 256, 0, stream>>>(x, lnf_s, lnf_b, out_x, nullptr);
}